// Round 3
// baseline (2682.411 us; speedup 1.0000x reference)
//
#include <hip/hip_runtime.h>
#include <hip/hip_bf16.h>
#include <math.h>

// GRU encoder: B=512, T=128, V=128, E=512, H=512, L=2
// Round 5: persistent kernel with FENCE-IMMUNE WEIGHTS IN LDS.
//  Round-4 counters showed 498MB HBM fetch = weights re-fetched every
//  superstep because the grid-barrier __threadfence invalidates L2.
//  Now: each block loads its weight slice into LDS ONCE (96KB dynamic),
//  steady-state loop reads B-frags from LDS (swizzled, conflict-free) and
//  A-frags (h state) global->VGPR directly. Zero __syncthreads and zero
//  weight traffic per timestep.
//  - layer0: 64 blocks, 128b x 32h, K=512 (h@Wh0^T); gi0 via tbl[v] (V=128).
//  - layer1: 128 blocks, 128b x 16h, K=1024 ([h0|h1]@[Wi1|Wh1]^T fused).
//  - 4 independent batch-groups of 48 blocks, each with its own barrier.
//  - all threads drain vmcnt(0) before barrier arrival (store visibility).
//  - f32 h carried in registers; bf16 shadow ping-pongs in ws.

#define BB 512
#define TT 128
#define VV 128
#define EE 512
#define HH 512
#define LL 2
#define BH (BB*HH)

#define NBLK 192
#define GS   48          // blocks per barrier group (16 L0 + 32 L1)

typedef short s16x8 __attribute__((ext_vector_type(8)));
typedef float f32x4 __attribute__((ext_vector_type(4)));

// ---- ws layout (bf16 elems) ----
#define W_SZ    (3*HH*EE)                         // 786432 per matrix
#define WH0_OFF 0
#define WI1_OFF (W_SZ)
#define WH1_OFF (2*W_SZ)
#define HBF_OFF (3*W_SZ)
#define HBF_SZ  (4*BH)                            // [L][2][B][H] ping-pong
#define TBL_BYTE ((size_t)(3*W_SZ + HBF_SZ)*2)    // 6815744
#define TBL_SZ   (VV*3*HH)                        // 196608 f32
#define BAR_BYTE (TBL_BYTE + (size_t)TBL_SZ*4)    // 7602176

#define MFMA(a,b,c) __builtin_amdgcn_mfma_f32_16x16x32_bf16((a),(b),(c),0,0,0)

// fused prep: 3 weight matrices + 2 h0 slabs f32->bf16
#define PREP_N (3*W_SZ + 2*BH)
__global__ __launch_bounds__(256) void prep_bf16(
    const float* __restrict__ w_ih, const float* __restrict__ w_hh,
    const float* __restrict__ h0, __hip_bfloat16* __restrict__ wsb)
{
    const int i = blockIdx.x * 256 + threadIdx.x;
    if (i >= PREP_N) return;
    float v; int dst;
    if (i < W_SZ)            { v = w_hh[i];                 dst = i; }
    else if (i < 2*W_SZ)     { v = w_ih[W_SZ + i - W_SZ];   dst = i; }
    else if (i < 3*W_SZ)     { v = w_hh[W_SZ + i - 2*W_SZ]; dst = i; }
    else if (i < 3*W_SZ+BH)  { v = h0[i - 3*W_SZ];          dst = HBF_OFF + BH + (i - 3*W_SZ); }
    else                     { v = h0[i - 3*W_SZ];          dst = HBF_OFF + 3*BH + (i - 3*W_SZ - BH); }
    wsb[dst] = __float2bfloat16(v);
}

// gi0_table[v][col] = dot(emb[v], w_ih0[col]) + b_ih0[col]   (full f32)
__global__ __launch_bounds__(256) void build_gi0(
    const float* __restrict__ emb, const float* __restrict__ w_ih,
    const float* __restrict__ b_ih, float* __restrict__ tbl)
{
    __shared__ __align__(16) float e[EE];
    const int v   = blockIdx.y;
    const int col = blockIdx.x * 256 + threadIdx.x;   // 0..1535
    for (int i = threadIdx.x; i < EE; i += 256) e[i] = emb[v * EE + i];
    __syncthreads();
    const float4* w4 = (const float4*)(w_ih + (size_t)col * EE);
    const float4* e4 = (const float4*)e;
    float acc = 0.f;
    #pragma unroll 8
    for (int k = 0; k < EE/4; ++k) {
        float4 wv = w4[k], ev = e4[k];
        acc += wv.x*ev.x + wv.y*ev.y + wv.z*ev.z + wv.w*ev.w;
    }
    tbl[v * (3*HH) + col] = acc + b_ih[col];
}

__device__ __forceinline__ float sigm(float x) { return 1.f / (1.f + __expf(-x)); }
__device__ __forceinline__ float tanh_f(float x) {
    float e2 = __expf(2.f * x);
    return 1.f - 2.f / (e2 + 1.f);
}

// per-group barrier: base[0]=count, base[32]=gen, base[64]=abort
// Anti-hang: spinners poll abort; timeout poisons. Worst case = wrong
// answer, never a wedged GPU.
__device__ __forceinline__ void grid_sync(unsigned* base) {
    asm volatile("s_waitcnt vmcnt(0)" ::: "memory");   // all threads: stores done
    __syncthreads();
    if (threadIdx.x == 0) {
        unsigned* cnt = base;
        unsigned* gen = base + 32;
        unsigned* abt = base + 64;
        if (__hip_atomic_load(abt, __ATOMIC_RELAXED, __HIP_MEMORY_SCOPE_AGENT) == 0u) {
            unsigned g = __hip_atomic_load(gen, __ATOMIC_RELAXED, __HIP_MEMORY_SCOPE_AGENT);
            unsigned a = __hip_atomic_fetch_add(cnt, 1u, __ATOMIC_RELEASE, __HIP_MEMORY_SCOPE_AGENT);
            if (a == (unsigned)(GS - 1)) {
                __hip_atomic_store(cnt, 0u, __ATOMIC_RELAXED, __HIP_MEMORY_SCOPE_AGENT);
                __hip_atomic_store(gen, g + 1u, __ATOMIC_RELEASE, __HIP_MEMORY_SCOPE_AGENT);
            } else {
                int spins = 0;
                while (__hip_atomic_load(gen, __ATOMIC_RELAXED, __HIP_MEMORY_SCOPE_AGENT) == g) {
                    if (__hip_atomic_load(abt, __ATOMIC_RELAXED, __HIP_MEMORY_SCOPE_AGENT) != 0u)
                        break;
                    __builtin_amdgcn_s_sleep(2);
                    if (++spins > (1 << 20)) {
                        __hip_atomic_store(abt, 1u, __ATOMIC_RELAXED, __HIP_MEMORY_SCOPE_AGENT);
                        break;
                    }
                }
            }
        }
        __threadfence();   // agent fence: wbl2 + inv (L2 coherence point)
    }
    __syncthreads();
}

__global__ __launch_bounds__(512) void gru_persist(
    const int*   __restrict__ input,   // [B,T]
    const float* __restrict__ h0,      // [L,B,H] f32
    const float* __restrict__ b_ih,    // [L,3H]
    const float* __restrict__ b_hh,    // [L,3H]
    const __hip_bfloat16* __restrict__ wh0,  // [3H,512] bf16
    const __hip_bfloat16* __restrict__ wi1,
    const __hip_bfloat16* __restrict__ wh1,
    const float* __restrict__ tbl,           // [V,3H]
    __hip_bfloat16* __restrict__ hbf,        // [L][2][B][H]
    float*       __restrict__ out,           // [T,L,B,H]
    unsigned*    __restrict__ bar)
{
    extern __shared__ __align__(16) char lds[];   // 96KB weight slice

    const int tid  = threadIdx.x;
    const int w    = tid >> 6;         // wave 0..7
    const int lane = tid & 63;
    const int l15  = lane & 15;
    const int lg   = lane >> 4;
    const int bid  = blockIdx.x;

    if (bid < 64) {
        // ============ layer 0: h@Wh0^T, K=512, 128b x 32h ============
        const int bt = bid >> 4, ht = bid & 15;    // 4 x 16
        unsigned* gbar = bar + bt * 128;
        const int B0 = bt * 128 + w * 16;
        const int hbase = ht * 32;

        // --- weight slice -> LDS, once.  rows lr = g*32+hl, 1024B each,
        //     16B block blk stored at blk ^ (lr&7) (bank-spread, bijective)
        for (int j = 0; j < 12; ++j) {
            int cidx = tid + 512 * j;              // 0..6143
            int lr = cidx >> 6, blk = cidx & 63;
            int g = lr >> 5, hl = lr & 31;
            s16x8 wv = *(const s16x8*)(wh0 + (size_t)(g*512 + hbase + hl)*512 + blk*8);
            *(s16x8*)(&lds[lr*1024 + ((blk ^ (lr & 7)) << 4)]) = wv;
        }
        __syncthreads();

        float bi_[2][3], bh_[2][3];
        #pragma unroll
        for (int nt = 0; nt < 2; ++nt) {
            const int h = hbase + nt*16 + l15;
            #pragma unroll
            for (int g = 0; g < 3; ++g) bh_[nt][g] = b_hh[g*512 + h];
        }
        (void)bi_;

        float hreg[2][4];
        #pragma unroll
        for (int nt = 0; nt < 2; ++nt)
            #pragma unroll
            for (int r = 0; r < 4; ++r)
                hreg[nt][r] = h0[(size_t)(B0 + lg*4 + r)*HH + hbase + nt*16 + l15];

        for (int t = 0; t < TT; ++t) {
            const __hip_bfloat16* hsrc = hbf + (size_t)((t + 1) & 1) * BH;

            // gi0 gather (independent of h -> overlaps MFMA chain)
            float tv[2][3][4];
            #pragma unroll
            for (int r = 0; r < 4; ++r) {
                int vv = input[(B0 + lg*4 + r)*TT + t];
                const float* tp = tbl + (size_t)vv*(3*HH) + hbase + l15;
                #pragma unroll
                for (int g = 0; g < 3; ++g)
                    #pragma unroll
                    for (int nt = 0; nt < 2; ++nt)
                        tv[nt][g][r] = tp[g*512 + nt*16];
            }

            f32x4 acc[2][3];
            #pragma unroll
            for (int nt = 0; nt < 2; ++nt)
                #pragma unroll
                for (int g = 0; g < 3; ++g) acc[nt][g] = (f32x4)(0.f);

            #pragma unroll
            for (int c = 0; c < 16; ++c) {
                const s16x8 a = *(const s16x8*)(hsrc + (size_t)(B0 + l15)*512 + c*32 + lg*8);
                #pragma unroll
                for (int nt = 0; nt < 2; ++nt)
                    #pragma unroll
                    for (int g = 0; g < 3; ++g) {
                        int lr = g*32 + nt*16 + l15;
                        s16x8 bf = *(const s16x8*)(&lds[lr*1024 + (((c*4 + lg) ^ (lr & 7)) << 4)]);
                        acc[nt][g] = MFMA(a, bf, acc[nt][g]);
                    }
            }

            float* outp = out + (size_t)(t * 2) * BH;
            __hip_bfloat16* hw = hbf + (size_t)(t & 1) * BH;
            #pragma unroll
            for (int nt = 0; nt < 2; ++nt) {
                const int h = hbase + nt*16 + l15;
                #pragma unroll
                for (int r = 0; r < 4; ++r) {
                    const int b = B0 + lg*4 + r;
                    float rg = sigm(acc[nt][0][r] + tv[nt][0][r] + bh_[nt][0]);
                    float zg = sigm(acc[nt][1][r] + tv[nt][1][r] + bh_[nt][1]);
                    float ng = tanh_f(tv[nt][2][r] + rg*(acc[nt][2][r] + bh_[nt][2]));
                    float hn = (1.f - zg)*ng + zg*hreg[nt][r];
                    hreg[nt][r] = hn;
                    outp[(size_t)b*HH + h] = hn;
                    hw[(size_t)b*HH + h] = __float2bfloat16(hn);
                }
            }
            grid_sync(gbar);
        }
    } else {
        // ======== layer 1: [h0|h1]@[Wi1|Wh1]^T, K=1024, 128b x 16h ========
        const int id = bid - 64;
        const int bt = id >> 5, ht = id & 31;      // 4 x 32
        unsigned* gbar = bar + bt * 128;
        const int B0 = bt * 128 + w * 16;
        const int hbase = ht * 16;

        // --- weights -> LDS: rows lr = g*16+hl, 2048B (K=1024: wi1|wh1)
        for (int j = 0; j < 12; ++j) {
            int cidx = tid + 512 * j;              // 0..6143
            int lr = cidx >> 7, blk = cidx & 127;
            int g = lr >> 4, hl = lr & 15;
            const __hip_bfloat16* src = (blk < 64) ? wi1 : wh1;
            s16x8 wv = *(const s16x8*)(src + (size_t)(g*512 + hbase + hl)*512 + (blk & 63)*8);
            *(s16x8*)(&lds[lr*2048 + ((blk ^ (lr & 7)) << 4)]) = wv;
        }
        __syncthreads();

        const int h = hbase + l15;
        const float bir = b_ih[1536 + h],       biz = b_ih[1536 + 512 + h],
                    bin = b_ih[1536 + 1024 + h];
        const float bhr = b_hh[1536 + h],       bhz = b_hh[1536 + 512 + h],
                    bhn = b_hh[1536 + 1024 + h];

        float hreg[4];
        #pragma unroll
        for (int r = 0; r < 4; ++r)
            hreg[r] = h0[(size_t)BH + (size_t)(B0 + lg*4 + r)*HH + h];

        grid_sync(gbar);   // wait for layer0@t=0
        for (int t = 0; t < TT; ++t) {
            const __hip_bfloat16* xsrc = hbf + (size_t)(t & 1) * BH;            // h0[t]
            const __hip_bfloat16* hsrc = hbf + (size_t)(2 + ((t + 1) & 1)) * BH; // h1[t-1]
            f32x4 ar = (f32x4)(0.f), az = (f32x4)(0.f), ani = (f32x4)(0.f), anh = (f32x4)(0.f);

            #pragma unroll
            for (int c = 0; c < 32; ++c) {
                const __hip_bfloat16* asrc = (c < 16) ? xsrc : hsrc;
                const s16x8 a = *(const s16x8*)(asrc + (size_t)(B0 + l15)*512 + (c & 15)*32 + lg*8);
                int lr0 = 0*16 + l15, lr1 = 1*16 + l15, lr2 = 2*16 + l15;
                s16x8 b0 = *(const s16x8*)(&lds[lr0*2048 + (((c*4 + lg) ^ (lr0 & 7)) << 4)]);
                s16x8 b1 = *(const s16x8*)(&lds[lr1*2048 + (((c*4 + lg) ^ (lr1 & 7)) << 4)]);
                s16x8 b2 = *(const s16x8*)(&lds[lr2*2048 + (((c*4 + lg) ^ (lr2 & 7)) << 4)]);
                ar = MFMA(a, b0, ar);
                az = MFMA(a, b1, az);
                if (c < 16) ani = MFMA(a, b2, ani);
                else        anh = MFMA(a, b2, anh);
            }

            float* outp = out + (size_t)(t * 2 + 1) * BH;
            __hip_bfloat16* hw = hbf + (size_t)(2 + (t & 1)) * BH;
            #pragma unroll
            for (int r = 0; r < 4; ++r) {
                float rg = sigm(ar[r] + bir + bhr);
                float zg = sigm(az[r] + biz + bhz);
                float ng = tanh_f(ani[r] + bin + rg*(anh[r] + bhn));
                float hn = (1.f - zg)*ng + zg*hreg[r];
                hreg[r] = hn;
                int b = B0 + lg*4 + r;
                outp[(size_t)b*HH + h] = hn;
                hw[(size_t)b*HH + h] = __float2bfloat16(hn);
            }
            if (t < TT - 1) grid_sync(gbar);
        }
    }
}

__global__ __launch_bounds__(256) void copy_final(
    const float* __restrict__ states, float* __restrict__ dst)
{
    const int i = blockIdx.x * 256 + threadIdx.x;   // L*B*H
    dst[i] = states[(size_t)(TT - 1) * LL * BH + i];
}

extern "C" void kernel_launch(void* const* d_in, const int* in_sizes, int n_in,
                              void* d_out, int out_size, void* d_ws, size_t ws_size,
                              hipStream_t stream) {
    const int*   input = (const int*)  d_in[0];
    const float* h0    = (const float*)d_in[1];
    const float* emb   = (const float*)d_in[2];
    const float* w_ih  = (const float*)d_in[3];
    const float* w_hh  = (const float*)d_in[4];
    const float* b_ih  = (const float*)d_in[5];
    const float* b_hh  = (const float*)d_in[6];
    float* out = (float*)d_out;

    __hip_bfloat16* wsb = (__hip_bfloat16*)d_ws;
    __hip_bfloat16* wh0 = wsb + WH0_OFF;
    __hip_bfloat16* wi1 = wsb + WI1_OFF;
    __hip_bfloat16* wh1 = wsb + WH1_OFF;
    __hip_bfloat16* hbf = wsb + HBF_OFF;
    float*    tbl = (float*)   ((char*)d_ws + TBL_BYTE);
    unsigned* bar = (unsigned*)((char*)d_ws + BAR_BYTE);

    hipMemsetAsync(bar, 0, 2048, stream);   // 4 groups x 512B (cnt/gen/abort)
    prep_bf16<<<(PREP_N + 255)/256, 256, 0, stream>>>(w_ih, w_hh, h0, wsb);
    build_gi0<<<dim3(6, VV), 256, 0, stream>>>(emb, w_ih, b_ih, tbl);

    gru_persist<<<NBLK, 512, 98304, stream>>>(input, h0, b_ih, b_hh,
                                              wh0, wi1, wh1, tbl, hbf, out, bar);

    copy_final<<<(LL*BH)/256, 256, 0, stream>>>(out, out + (size_t)TT * LL * BH);
}

// Round 4
// 2521.822 us; speedup vs baseline: 1.0637x; 1.0637x over previous
//
#include <hip/hip_runtime.h>
#include <hip/hip_bf16.h>
#include <math.h>

// GRU encoder: B=512, T=128, V=128, E=512, H=512, L=2
// Round 6: FENCE-FREE persistent kernel.
//  r4/r5 both sat at 18.5us/superstep: the grid barrier's __threadfence
//  (buffer_wbl2+buffer_inv) nuked L2 every step -> all post-barrier loads
//  were unhidden L3 misses (VGPR=64, 2 waves/SIMD, no MLP).
//  Now:
//   - h ping-pong exchange uses AGENT-scope relaxed atomics only:
//     stores = u32 (2 packed bf16 via shfl), loads = u64 pairs. These are
//     coherent at the IF/L3 point -> NO threadfence needed anywhere.
//   - barrier = all-relaxed atomics, monotonic arrival count (target GS*k,
//     no reset race), per-thread vmcnt(0) drain before arrival, abort bit
//     in gen word (worst case = fast wrong answer, never a hang).
//   - weights stay in LDS (96KB); tbl/input/bias stay warm in L2 forever.
//   - all A-frags for a step hoisted up front; __launch_bounds__(512,2)
//     for a 256-VGPR budget -> deep MLP.

#define BB 512
#define TT 128
#define VV 128
#define EE 512
#define HH 512
#define LL 2
#define BH (BB*HH)

#define NBLK 192
#define GS   48          // blocks per barrier group (16 L0 + 32 L1)
#define ABORT_BIT 0x80000000u

typedef short s16x8 __attribute__((ext_vector_type(8)));
typedef float f32x4 __attribute__((ext_vector_type(4)));

// ---- ws layout (bf16 elems) ----
#define W_SZ    (3*HH*EE)                         // 786432 per matrix
#define WH0_OFF 0
#define WI1_OFF (W_SZ)
#define WH1_OFF (2*W_SZ)
#define HBF_OFF (3*W_SZ)
#define HBF_SZ  (4*BH)                            // [L][2][B][H] ping-pong
#define TBL_BYTE ((size_t)(3*W_SZ + HBF_SZ)*2)    // 6815744
#define TBL_SZ   (VV*3*HH)                        // 196608 f32
#define BAR_BYTE (TBL_BYTE + (size_t)TBL_SZ*4)    // 7602176

#define MFMA(a,b,c) __builtin_amdgcn_mfma_f32_16x16x32_bf16((a),(b),(c),0,0,0)

// fused prep: 3 weight matrices + 2 h0 slabs f32->bf16
#define PREP_N (3*W_SZ + 2*BH)
__global__ __launch_bounds__(256) void prep_bf16(
    const float* __restrict__ w_ih, const float* __restrict__ w_hh,
    const float* __restrict__ h0, __hip_bfloat16* __restrict__ wsb)
{
    const int i = blockIdx.x * 256 + threadIdx.x;
    if (i >= PREP_N) return;
    float v; int dst;
    if (i < W_SZ)            { v = w_hh[i];                 dst = i; }
    else if (i < 2*W_SZ)     { v = w_ih[W_SZ + i - W_SZ];   dst = i; }
    else if (i < 3*W_SZ)     { v = w_hh[W_SZ + i - 2*W_SZ]; dst = i; }
    else if (i < 3*W_SZ+BH)  { v = h0[i - 3*W_SZ];          dst = HBF_OFF + BH + (i - 3*W_SZ); }
    else                     { v = h0[i - 3*W_SZ];          dst = HBF_OFF + 3*BH + (i - 3*W_SZ - BH); }
    wsb[dst] = __float2bfloat16(v);
}

// gi0_table[v][col] = dot(emb[v], w_ih0[col]) + b_ih0[col]   (full f32)
__global__ __launch_bounds__(256) void build_gi0(
    const float* __restrict__ emb, const float* __restrict__ w_ih,
    const float* __restrict__ b_ih, float* __restrict__ tbl)
{
    __shared__ __align__(16) float e[EE];
    const int v   = blockIdx.y;
    const int col = blockIdx.x * 256 + threadIdx.x;   // 0..1535
    for (int i = threadIdx.x; i < EE; i += 256) e[i] = emb[v * EE + i];
    __syncthreads();
    const float4* w4 = (const float4*)(w_ih + (size_t)col * EE);
    const float4* e4 = (const float4*)e;
    float acc = 0.f;
    #pragma unroll 8
    for (int k = 0; k < EE/4; ++k) {
        float4 wv = w4[k], ev = e4[k];
        acc += wv.x*ev.x + wv.y*ev.y + wv.z*ev.z + wv.w*ev.w;
    }
    tbl[v * (3*HH) + col] = acc + b_ih[col];
}

__device__ __forceinline__ float sigm(float x) { return 1.f / (1.f + __expf(-x)); }
__device__ __forceinline__ float tanh_f(float x) {
    float e2 = __expf(2.f * x);
    return 1.f - 2.f / (e2 + 1.f);
}

// coherent (agent-scope) 16B load as two u64 relaxed atomics
__device__ __forceinline__ s16x8 gldc16(const __hip_bfloat16* p) {
    union { struct { unsigned long long a, b; } q; s16x8 v; } u;
    u.q.a = __hip_atomic_load((const unsigned long long*)p,
                              __ATOMIC_RELAXED, __HIP_MEMORY_SCOPE_AGENT);
    u.q.b = __hip_atomic_load(((const unsigned long long*)p) + 1,
                              __ATOMIC_RELAXED, __HIP_MEMORY_SCOPE_AGENT);
    return u.v;
}

__device__ __forceinline__ unsigned short bf16b(float f) {
    union { __hip_bfloat16 h; unsigned short u; } u;
    u.h = __float2bfloat16(f);
    return u.u;
}

// fence-free grid barrier. base[0]=arrival count (monotonic, target GS*k),
// base[32]=gen (released generation; bit31 = abort).
__device__ __forceinline__ void grid_sync(unsigned* base, unsigned k) {
    asm volatile("s_waitcnt vmcnt(0)" ::: "memory");   // own stores durable
    __syncthreads();
    if (threadIdx.x == 0) {
        unsigned* cnt = base;
        unsigned* gen = base + 32;
        unsigned v0 = __hip_atomic_load(gen, __ATOMIC_RELAXED, __HIP_MEMORY_SCOPE_AGENT);
        if (!(v0 & ABORT_BIT)) {
            unsigned a = __hip_atomic_fetch_add(cnt, 1u, __ATOMIC_RELAXED, __HIP_MEMORY_SCOPE_AGENT);
            if (a == (unsigned)GS * k - 1u) {
                __hip_atomic_store(gen, k, __ATOMIC_RELAXED, __HIP_MEMORY_SCOPE_AGENT);
            } else {
                int spins = 0;
                for (;;) {
                    unsigned v = __hip_atomic_load(gen, __ATOMIC_RELAXED, __HIP_MEMORY_SCOPE_AGENT);
                    if ((v & ABORT_BIT) || v >= k) break;
                    if (++spins > (1 << 21)) {   // poison & bail; sticky abort
                        __hip_atomic_store(gen, ABORT_BIT | k, __ATOMIC_RELAXED, __HIP_MEMORY_SCOPE_AGENT);
                        break;
                    }
                }
            }
        }
    }
    __syncthreads();
}

__global__ __launch_bounds__(512, 2) void gru_persist(
    const int*   __restrict__ input,   // [B,T]
    const float* __restrict__ h0,      // [L,B,H] f32
    const float* __restrict__ b_ih,    // [L,3H]
    const float* __restrict__ b_hh,    // [L,3H]
    const __hip_bfloat16* __restrict__ wh0,  // [3H,512] bf16
    const __hip_bfloat16* __restrict__ wi1,
    const __hip_bfloat16* __restrict__ wh1,
    const float* __restrict__ tbl,           // [V,3H]
    __hip_bfloat16* __restrict__ hbf,        // [L][2][B][H]
    float*       __restrict__ out,           // [T,L,B,H]
    unsigned*    __restrict__ bar)
{
    extern __shared__ __align__(16) char lds[];   // 96KB weight slice

    const int tid  = threadIdx.x;
    const int w    = tid >> 6;         // wave 0..7
    const int lane = tid & 63;
    const int l15  = lane & 15;
    const int lg   = lane >> 4;
    const int bid  = blockIdx.x;

    if (bid < 64) {
        // ============ layer 0: h@Wh0^T, K=512, 128b x 32h ============
        const int bt = bid >> 4, ht = bid & 15;    // 4 x 16
        unsigned* gbar = bar + bt * 128;
        const int B0 = bt * 128 + w * 16;
        const int hbase = ht * 32;

        // weight slice -> LDS once; 16B block blk stored at blk^(lr&7)
        for (int j = 0; j < 12; ++j) {
            int cidx = tid + 512 * j;              // 0..6143
            int lr = cidx >> 6, blk = cidx & 63;
            int g = lr >> 5, hl = lr & 31;
            s16x8 wv = *(const s16x8*)(wh0 + (size_t)(g*512 + hbase + hl)*512 + blk*8);
            *(s16x8*)(&lds[lr*1024 + ((blk ^ (lr & 7)) << 4)]) = wv;
        }
        __syncthreads();

        float bh_[2][3];
        #pragma unroll
        for (int nt = 0; nt < 2; ++nt)
            #pragma unroll
            for (int g = 0; g < 3; ++g)
                bh_[nt][g] = b_hh[g*512 + hbase + nt*16 + l15];

        float hreg[2][4];
        #pragma unroll
        for (int nt = 0; nt < 2; ++nt)
            #pragma unroll
            for (int r = 0; r < 4; ++r)
                hreg[nt][r] = h0[(size_t)(B0 + lg*4 + r)*HH + hbase + nt*16 + l15];

        unsigned myk = 0;
        for (int t = 0; t < TT; ++t) {
            const __hip_bfloat16* hsrc = hbf + (size_t)((t + 1) & 1) * BH;

            // all A-frags coherent, hoisted for MLP
            s16x8 a[16];
            #pragma unroll
            for (int c = 0; c < 16; ++c)
                a[c] = gldc16(hsrc + (size_t)(B0 + l15)*512 + c*32 + lg*8);

            // gi0 gather (L2-warm now)
            float tv[2][3][4];
            #pragma unroll
            for (int r = 0; r < 4; ++r) {
                int vv = input[(B0 + lg*4 + r)*TT + t];
                const float* tp = tbl + (size_t)vv*(3*HH) + hbase + l15;
                #pragma unroll
                for (int g = 0; g < 3; ++g)
                    #pragma unroll
                    for (int nt = 0; nt < 2; ++nt)
                        tv[nt][g][r] = tp[g*512 + nt*16];
            }

            f32x4 acc[2][3];
            #pragma unroll
            for (int nt = 0; nt < 2; ++nt)
                #pragma unroll
                for (int g = 0; g < 3; ++g) acc[nt][g] = (f32x4)(0.f);

            #pragma unroll
            for (int c = 0; c < 16; ++c)
                #pragma unroll
                for (int nt = 0; nt < 2; ++nt)
                    #pragma unroll
                    for (int g = 0; g < 3; ++g) {
                        int lr = g*32 + nt*16 + l15;
                        s16x8 bf = *(const s16x8*)(&lds[lr*1024 + (((c*4 + lg) ^ (lr & 7)) << 4)]);
                        acc[nt][g] = MFMA(a[c], bf, acc[nt][g]);
                    }

            float* outp = out + (size_t)(t * 2) * BH;
            __hip_bfloat16* hw = hbf + (size_t)(t & 1) * BH;
            #pragma unroll
            for (int nt = 0; nt < 2; ++nt) {
                const int hcol = hbase + nt*16 + l15;
                #pragma unroll
                for (int r = 0; r < 4; ++r) {
                    const int b = B0 + lg*4 + r;
                    float rg = sigm(acc[nt][0][r] + tv[nt][0][r] + bh_[nt][0]);
                    float zg = sigm(acc[nt][1][r] + tv[nt][1][r] + bh_[nt][1]);
                    float ng = tanh_f(tv[nt][2][r] + rg*(acc[nt][2][r] + bh_[nt][2]));
                    float hn = (1.f - zg)*ng + zg*hreg[nt][r];
                    hreg[nt][r] = hn;
                    outp[(size_t)b*HH + hcol] = hn;
                    float nb = __shfl_down(hn, 1);     // col hcol+1, same b
                    if ((l15 & 1) == 0) {
                        unsigned pv = (unsigned)bf16b(hn) | ((unsigned)bf16b(nb) << 16);
                        __hip_atomic_store((unsigned*)(hw + (size_t)b*HH + hcol), pv,
                                           __ATOMIC_RELAXED, __HIP_MEMORY_SCOPE_AGENT);
                    }
                }
            }
            grid_sync(gbar, ++myk);
        }
    } else {
        // ======== layer 1: [h0|h1]@[Wi1|Wh1]^T, K=1024, 128b x 16h ========
        const int id = bid - 64;
        const int bt = id >> 5, ht = id & 31;      // 4 x 32
        unsigned* gbar = bar + bt * 128;
        const int B0 = bt * 128 + w * 16;
        const int hbase = ht * 16;

        for (int j = 0; j < 12; ++j) {
            int cidx = tid + 512 * j;              // 0..6143
            int lr = cidx >> 7, blk = cidx & 127;
            int g = lr >> 4, hl = lr & 15;
            const __hip_bfloat16* src = (blk < 64) ? wi1 : wh1;
            s16x8 wv = *(const s16x8*)(src + (size_t)(g*512 + hbase + hl)*512 + (blk & 63)*8);
            *(s16x8*)(&lds[lr*2048 + ((blk ^ (lr & 7)) << 4)]) = wv;
        }
        __syncthreads();

        const int hcol = hbase + l15;
        const float bir = b_ih[1536 + hcol],       biz = b_ih[1536 + 512 + hcol],
                    bin = b_ih[1536 + 1024 + hcol];
        const float bhr = b_hh[1536 + hcol],       bhz = b_hh[1536 + 512 + hcol],
                    bhn = b_hh[1536 + 1024 + hcol];

        float hreg[4];
        #pragma unroll
        for (int r = 0; r < 4; ++r)
            hreg[r] = h0[(size_t)BH + (size_t)(B0 + lg*4 + r)*HH + hcol];

        unsigned myk = 0;
        grid_sync(gbar, ++myk);   // wait for layer0@t=0
        for (int t = 0; t < TT; ++t) {
            const __hip_bfloat16* xsrc = hbf + (size_t)(t & 1) * BH;             // h0[t]
            const __hip_bfloat16* hsrc = hbf + (size_t)(2 + ((t + 1) & 1)) * BH; // h1[t-1]

            s16x8 aa[32];
            #pragma unroll
            for (int c = 0; c < 32; ++c) {
                const __hip_bfloat16* asrc = (c < 16) ? xsrc : hsrc;
                aa[c] = gldc16(asrc + (size_t)(B0 + l15)*512 + (c & 15)*32 + lg*8);
            }

            f32x4 ar = (f32x4)(0.f), az = (f32x4)(0.f), ani = (f32x4)(0.f), anh = (f32x4)(0.f);
            #pragma unroll
            for (int c = 0; c < 32; ++c) {
                int lr0 = l15, lr1 = 16 + l15, lr2 = 32 + l15;
                s16x8 b0 = *(const s16x8*)(&lds[lr0*2048 + (((c*4 + lg) ^ (lr0 & 7)) << 4)]);
                s16x8 b1 = *(const s16x8*)(&lds[lr1*2048 + (((c*4 + lg) ^ (lr1 & 7)) << 4)]);
                s16x8 b2 = *(const s16x8*)(&lds[lr2*2048 + (((c*4 + lg) ^ (lr2 & 7)) << 4)]);
                ar = MFMA(aa[c], b0, ar);
                az = MFMA(aa[c], b1, az);
                if (c < 16) ani = MFMA(aa[c], b2, ani);
                else        anh = MFMA(aa[c], b2, anh);
            }

            float* outp = out + (size_t)(t * 2 + 1) * BH;
            __hip_bfloat16* hw = hbf + (size_t)(2 + (t & 1)) * BH;
            #pragma unroll
            for (int r = 0; r < 4; ++r) {
                float rg = sigm(ar[r] + bir + bhr);
                float zg = sigm(az[r] + biz + bhz);
                float ng = tanh_f(ani[r] + bin + rg*(anh[r] + bhn));
                float hn = (1.f - zg)*ng + zg*hreg[r];
                hreg[r] = hn;
                int b = B0 + lg*4 + r;
                outp[(size_t)b*HH + hcol] = hn;
                float nb = __shfl_down(hn, 1);
                if ((l15 & 1) == 0) {
                    unsigned pv = (unsigned)bf16b(hn) | ((unsigned)bf16b(nb) << 16);
                    __hip_atomic_store((unsigned*)(hw + (size_t)b*HH + hcol), pv,
                                       __ATOMIC_RELAXED, __HIP_MEMORY_SCOPE_AGENT);
                }
            }
            if (t < TT - 1) grid_sync(gbar, ++myk);
        }
    }
}

__global__ __launch_bounds__(256) void copy_final(
    const float* __restrict__ states, float* __restrict__ dst)
{
    const int i = blockIdx.x * 256 + threadIdx.x;   // L*B*H
    dst[i] = states[(size_t)(TT - 1) * LL * BH + i];
}

extern "C" void kernel_launch(void* const* d_in, const int* in_sizes, int n_in,
                              void* d_out, int out_size, void* d_ws, size_t ws_size,
                              hipStream_t stream) {
    const int*   input = (const int*)  d_in[0];
    const float* h0    = (const float*)d_in[1];
    const float* emb   = (const float*)d_in[2];
    const float* w_ih  = (const float*)d_in[3];
    const float* w_hh  = (const float*)d_in[4];
    const float* b_ih  = (const float*)d_in[5];
    const float* b_hh  = (const float*)d_in[6];
    float* out = (float*)d_out;

    __hip_bfloat16* wsb = (__hip_bfloat16*)d_ws;
    __hip_bfloat16* wh0 = wsb + WH0_OFF;
    __hip_bfloat16* wi1 = wsb + WI1_OFF;
    __hip_bfloat16* wh1 = wsb + WH1_OFF;
    __hip_bfloat16* hbf = wsb + HBF_OFF;
    float*    tbl = (float*)   ((char*)d_ws + TBL_BYTE);
    unsigned* bar = (unsigned*)((char*)d_ws + BAR_BYTE);

    hipMemsetAsync(bar, 0, 2048, stream);   // 4 groups x 512B (cnt/gen)
    prep_bf16<<<(PREP_N + 255)/256, 256, 0, stream>>>(w_ih, w_hh, h0, wsb);
    build_gi0<<<dim3(6, VV), 256, 0, stream>>>(emb, w_ih, b_ih, tbl);

    gru_persist<<<NBLK, 512, 98304, stream>>>(input, h0, b_ih, b_hh,
                                              wh0, wi1, wh1, tbl, hbf, out, bar);

    copy_final<<<(LL*BH)/256, 256, 0, stream>>>(out, out + (size_t)TT * LL * BH);
}